// Round 6
// baseline (63.528 us; speedup 1.0000x reference)
//
#include <hip/hip_runtime.h>

#define BSZ 512
#define KOUT 960
// e^{+19.3}, e^{-19.3}: exp-domain images of the reference's LLR clip.
#define EMAX 2.4092698e8f
#define EMIN 4.1506346e-9f

// Exp-domain boxplus: (1 + Ex*Ey)/(Ex+Ey), args clamped to the clip range.
// v_rcp_f32 ~1 ulp. boxpE(1,y)==1 to 1 ulp (num,den round identically).
__device__ __forceinline__ float boxpE(float ex, float ey) {
    ex = fminf(fmaxf(ex, EMIN), EMAX);
    ey = fminf(fmaxf(ey, EMIN), EMAX);
    return __builtin_fmaf(ex, ey, 1.0f) * __builtin_amdgcn_rcpf(ex + ey);
}

// ONE WAVE PER BATCH ITEM. Position p = 64*j + lane, j = 0..15 register
// planes. Stage distance 2^s: s<=5 -> lane-xor (__shfl_xor); s>=6 -> plane
// index xor (free register select). Zero LDS, zero barriers.
// R sparsity: supp r[1..6]=[0,64)=plane0, r[7]=planes{0,1}, r[8]={0..3},
// r[9]={0..7}. Backward restarts from llr each iter and a-side r-terms are 0
// on the support region, so supports L[9](j<8), L[8](j<4), L[7](j<2),
// L[6](j=0) are ITERATION-INVARIANT -> computed once, intra-lane.
// Per-iteration carried state: plane-0 recurrence only (fwd r[1..6] 6 boxp +
// bwd L[5..1] 5 boxp, all shuffles). Iteration 9 runs the full pipeline in
// registers; its a-side values are the invariants (bit-identical reuse).
__global__ __launch_bounds__(64) void polar_bp(const float* __restrict__ in,
                                               float* __restrict__ out) {
    const int lane = threadIdx.x;
    const float* inb = in + (size_t)blockIdx.x * 1024;

    // llr_ch = -in  ->  E = e^{-in}
    float llr[16];
#pragma unroll
    for (int j = 0; j < 16; ++j) llr[j] = __expf(-inb[64 * j + lane]);

    // ---- prologue: iteration-invariant a-side backward chain (r-free) ----
    float L9i[8], L8i[4], L7i[2], L6i;
#pragma unroll
    for (int j = 0; j < 8; ++j) L9i[j] = boxpE(llr[j], llr[j + 8]);
#pragma unroll
    for (int j = 0; j < 4; ++j) L8i[j] = boxpE(L9i[j], L9i[j + 4]);
    L7i[0] = boxpE(L8i[0], L8i[2]);
    L7i[1] = boxpE(L8i[1], L8i[3]);
    L6i = boxpE(L7i[0], L7i[1]);

    // ---- plane-0 recurrence: iters 0..8 full, iter 9 forward only ----
    float Ls[7], Rs[6], r6 = 1.f;
#pragma unroll
    for (int s = 0; s < 7; ++s) Ls[s] = 1.f;       // msg_l0 = zeros
#pragma unroll 1
    for (int it = 0; it < 10; ++it) {
        float r = EMAX;                            // r[0] = LLRMAX on frozen set
#pragma unroll
        for (int s = 0; s <= 5; ++s) {
            float lp = __shfl_xor(Ls[s + 1], 1 << s, 64);
            float rp = __shfl_xor(r, 1 << s, 64);
            bool isB = (lane >> s) & 1;
            float x = isB ? rp : r;                // a: boxp(r, lp*rp); b: boxp(rp,lp)*r
            float y = isB ? lp : lp * rp;
            float c = boxpE(x, y);
            r = isB ? c * r : c;
            if (s <= 4) Rs[s + 1] = r;
        }
        r6 = r;
        if (it == 9) break;                        // final fwd feeds full pass
        float Lc = L6i;                            // bwd stages 5..1
#pragma unroll
        for (int s = 5; s >= 1; --s) {
            const int m = 1 << s;
            float rp = __shfl_xor(Rs[s], m, 64);
            float lp = __shfl_xor(Lc, m, 64);
            bool isB = (lane >> s) & 1;
            float x = isB ? rp : Lc;
            float y = isB ? lp : lp * rp;
            float c = boxpE(x, y);
            Lc = isB ? c * Lc : c;
            Ls[s] = Lc;
        }
        Ls[6] = L6i;
    }

    // ---- final iteration, all in registers ----
    // r-chain: r_{s+1}[p] = boxp(r_s[p & (2^s-1)], L_{s+1}[p ^ 2^s]), s>=6
    float r7[2], r8[4], r9[8];
#pragma unroll
    for (int j = 0; j < 2; ++j) r7[j] = boxpE(r6, L7i[j ^ 1]);
#pragma unroll
    for (int j = 0; j < 4; ++j) r8[j] = boxpE(r7[j & 1], L8i[j ^ 2]);
#pragma unroll
    for (int j = 0; j < 8; ++j) r9[j] = boxpE(r8[j & 3], L9i[j ^ 4]);

    float Lc[16];
    // stage 9 (j^8): a-side j<8 = L9i (invariant); b-side j>=8
#pragma unroll
    for (int j = 0; j < 8; ++j) Lc[j] = L9i[j];
#pragma unroll
    for (int j = 8; j < 16; ++j) Lc[j] = boxpE(r9[j - 8], llr[j - 8]) * llr[j];

    // stage 8 (j^4): a j<4 = L8i; b j=4..7 uses r8 and old a = L9i;
    // a j=8..11 r-free; b j=12..15 unchanged (r=0).
    {
        float b4 = boxpE(r8[0], L9i[0]) * Lc[4];
        float b5 = boxpE(r8[1], L9i[1]) * Lc[5];
        float b6 = boxpE(r8[2], L9i[2]) * Lc[6];
        float b7 = boxpE(r8[3], L9i[3]) * Lc[7];
        float a8 = boxpE(Lc[8], Lc[12]);
        float a9 = boxpE(Lc[9], Lc[13]);
        float a10 = boxpE(Lc[10], Lc[14]);
        float a11 = boxpE(Lc[11], Lc[15]);
        Lc[0] = L8i[0]; Lc[1] = L8i[1]; Lc[2] = L8i[2]; Lc[3] = L8i[3];
        Lc[4] = b4; Lc[5] = b5; Lc[6] = b6; Lc[7] = b7;
        Lc[8] = a8; Lc[9] = a9; Lc[10] = a10; Lc[11] = a11;
    }

    // stage 7 (j^2): a j=0,1 = L7i; b j=2,3 uses r7 and old a = L8i;
    // a j in {4,5,8,9,12,13} r-free; b j in {6,7,10,11,14,15} unchanged.
    {
        float b2 = boxpE(r7[0], L8i[0]) * Lc[2];
        float b3 = boxpE(r7[1], L8i[1]) * Lc[3];
        float a4 = boxpE(Lc[4], Lc[6]);
        float a5 = boxpE(Lc[5], Lc[7]);
        float a8 = boxpE(Lc[8], Lc[10]);
        float a9 = boxpE(Lc[9], Lc[11]);
        float a12 = boxpE(Lc[12], Lc[14]);
        float a13 = boxpE(Lc[13], Lc[15]);
        Lc[0] = L7i[0]; Lc[1] = L7i[1];
        Lc[2] = b2; Lc[3] = b3;
        Lc[4] = a4; Lc[5] = a5; Lc[8] = a8; Lc[9] = a9;
        Lc[12] = a12; Lc[13] = a13;
    }

    // stage 6 (j^1): a j=0 = L6i; b j=1 uses r6 and old a = L7i[0];
    // a even j>=2 r-free; b odd j>=3 unchanged.
    {
        float b1 = boxpE(r6, L7i[0]) * Lc[1];
        float a2 = boxpE(Lc[2], Lc[3]);
        float a4 = boxpE(Lc[4], Lc[5]);
        float a6 = boxpE(Lc[6], Lc[7]);
        float a8 = boxpE(Lc[8], Lc[9]);
        float a10 = boxpE(Lc[10], Lc[11]);
        float a12 = boxpE(Lc[12], Lc[13]);
        float a14 = boxpE(Lc[14], Lc[15]);
        Lc[0] = L6i; Lc[1] = b1;
        Lc[2] = a2; Lc[4] = a4; Lc[6] = a6; Lc[8] = a8;
        Lc[10] = a10; Lc[12] = a12; Lc[14] = a14;
    }

    // stages 5..1 (lane butterflies); r support = plane 0 only (iter-9 Rs).
#pragma unroll
    for (int s = 5; s >= 1; --s) {
        const int m = 1 << s;
        bool isB = (lane >> s) & 1;
        {
            float rp = __shfl_xor(Rs[s], m, 64);
            float lp = __shfl_xor(Lc[0], m, 64);
            float x = isB ? rp : Lc[0];
            float y = isB ? lp : lp * rp;
            float c = boxpE(x, y);
            Lc[0] = isB ? c * Lc[0] : c;
        }
#pragma unroll
        for (int j = 1; j < 16; ++j) {             // r=0: b-side unchanged
            float lp = __shfl_xor(Lc[j], m, 64);
            float c = boxpE(Lc[j], lp);
            Lc[j] = isB ? Lc[j] : c;
        }
    }

    // stage 0 -> output. Info positions p>=64 (planes j>=1) have r1=r2=0:
    // even p: -boxp(l1,l2); odd p: -l2. One v_log back to log domain.
    const size_t ob = (size_t)blockIdx.x * KOUT;
    const bool odd = lane & 1;
#pragma unroll
    for (int j = 1; j < 16; ++j) {
        float lp = __shfl_xor(Lc[j], 1, 64);
        float e = odd ? Lc[j] : boxpE(Lc[j], lp);
        out[ob + 64 * j + lane - 64] = -__logf(e);
    }
}

extern "C" void kernel_launch(void* const* d_in, const int* in_sizes, int n_in,
                              void* d_out, int out_size, void* d_ws, size_t ws_size,
                              hipStream_t stream) {
    const float* in = (const float*)d_in[0];
    float* out = (float*)d_out;
    polar_bp<<<BSZ, 64, 0, stream>>>(in, out);
}